// Round 8
// baseline (137.012 us; speedup 1.0000x reference)
//
#include <hip/hip_runtime.h>

// Dota2Eq3Embed round 8: fully-fused two-GEMM formulation, 8 units/block.
// Per unit u=(sample,side): v[i][d]=relu(embed[x[u*5+i]][d]).
// GEMM1 (per wave, own 32 s-cols): T[t][s] = sum_d Feat[t][d]*C_{bank(t)}[d][s]
//   t-layout: 0..34 triples(b0) | 48..62 S*pair(b1) | 64..78(b2) | 80..94(b3)
//             96..100 S2v(b4) | 101..105(b5) | 106..110(b6) | 111 S3(b7)
// GEMM2: E[cell][s] = sum_t M[cell][t]*T[t][s] + bias[s], M = constant 0/1
//   masks (9 ones/row) pinned in registers as MFMA A-frags. relu+mean over
//   125 cells done in-register on D-frags (2 shfl_xor). No OUT table, no
//   barrier between GEMM1/GEMM2 (wave reads only its own T rows).
// Then hbar -> wout (f32 VALU, WT transposed) -> per-unit FC partials -> pbuf.
// Grid 512 blocks = exactly 2 resident/CU: no block serialization.

typedef __attribute__((ext_vector_type(8))) short bf16x8;
typedef __attribute__((ext_vector_type(4))) float f32x4;

#define DEV __device__ __forceinline__
#define MFMA __builtin_amdgcn_mfma_f32_16x16x32_bf16

DEV constexpr int pid2c(int a, int b) {
  int x = a < b ? a : b, y = a < b ? b : a;
  return x * (9 - x) / 2 + y;                       // 15 pairs, lex
}
DEV constexpr int tid3c(int i, int j, int k) {
  int a = i, b = j, c = k, t;
  if (a > b) { t = a; a = b; b = t; }
  if (b > c) { t = b; b = c; c = t; }
  if (a > b) { t = a; a = b; b = t; }
  return a * (a * a - 18 * a + 107) / 6 + (b - a) * (11 - a - b) / 2 + (c - b);
}
DEV int pid2r(int x, int y) { if (x > y) { int t = x; x = y; y = t; } return x * (9 - x) / 2 + y; }
DEV int tid3r(int a, int b, int c) {
  int t;
  if (a > b) { t = a; a = b; b = t; }
  if (b > c) { t = b; b = c; c = t; }
  if (a > b) { t = a; a = b; b = t; }
  return a * (a * a - 18 * a + 107) / 6 + (b - a) * (11 - a - b) / 2 + (c - b);
}
DEV ushort f2bf(float f) {                          // RTNE
  unsigned u = __builtin_bit_cast(unsigned, f);
  return (ushort)((u + 0x7FFFu + ((u >> 16) & 1u)) >> 16);
}
// T chunk-swizzle: ushort index for logical (s, t), stride 128, 16B-chunk XOR
DEV int t_addr(int s, int t) {
  return s * 128 + ((((t >> 3) ^ (s & 7)) << 3) | (t & 7));
}

// ---------- prep: coefs -> bf16 CT[side][b][s][d]; wout -> WT[side][o][ss] ----------
__global__ __launch_bounds__(256)
void cvt_prep_kernel(const float* __restrict__ c1, const float* __restrict__ c2,
                     const float* __restrict__ w1, const float* __restrict__ w2,
                     ushort* __restrict__ ct, float* __restrict__ wt, int do_wt) {
  const int idx = blockIdx.x * 256 + threadIdx.x;
  if (idx < 2 * 8 * 128 * 64) {
    const int d = idx & 63, s = (idx >> 6) & 127, b = (idx >> 13) & 7, side = idx >> 16;
    ct[idx] = f2bf((side ? c2 : c1)[(d * 128 + s) * 8 + b]);
  } else if (do_wt) {
    const int j = idx - 131072;
    if (j < 2 * 128 * 128) {
      const int ss = j & 127, o = (j >> 7) & 127, side = j >> 14;
      wt[j] = (side ? w2 : w1)[ss * 128 + o];
    }
  }
}

__global__ __launch_bounds__(256, 2)
void dota2_eq3_fused(const int* __restrict__ x, const float* __restrict__ embed,
                     const float* __restrict__ bias1, const float* __restrict__ bias2,
                     const float* __restrict__ bout1, const float* __restrict__ bout2,
                     const float* __restrict__ wout1, const float* __restrict__ wout2,
                     const float* __restrict__ fcw,
                     const ushort* __restrict__ ct, const float* __restrict__ wt,
                     float* __restrict__ pbuf, int nunits)
{
  __shared__ __align__(16) ushort FT[80][72];     // feature rows (per unit)
  __shared__ __align__(16) ushort Tlds[128 * 128];// T[s][t] chunk-swizzled
  __shared__ __align__(16) float  hbar[128];
  __shared__ __align__(16) float  scratch[2][128];
  __shared__ __align__(16) float  fcp[4];

  const int tid = threadIdx.x;
  const int w   = tid >> 6;          // wave 0..3: owns s in [32w, 32w+32)
  const int l   = tid & 63;
  const int grp = l >> 4;
  const int lc  = l & 15;

  const int u0 = blockIdx.x * 8;
  const int nu = (nunits - u0 < 8) ? (nunits - u0) : 8;
  if (nu <= 0) return;

  // ---- block init: zero FT pad rows; zero T cols 112..127 ----
  for (int e = tid; e < 1728; e += 256) {          // 24 pad rows x 72
    const int r = e / 72, c = e - r * 72;
    const int row = (r < 13) ? (35 + r) : ((r == 13) ? 63 : (70 + r - 14));
    FT[row][c] = 0;
  }
  for (int e = tid; e < 2048; e += 256) {          // t 112..127 all s
    const int s = e >> 4, t = 112 + (e & 15);
    Tlds[t_addr(s, t)] = 0;
  }

  // ---- build Mstruct mask fragments (pinned registers, unit-independent) ----
  // cell = 16*mt + lc; 9 ones: t3, 3 pairs, m4(96+k), m5(101+j), m6(106+i), a7(111)
  unsigned msk[8][4];
  #pragma unroll
  for (int mt = 0; mt < 8; ++mt) {
    unsigned m0 = 0, m1 = 0, m2 = 0, m3 = 0;
    const int cell = 16 * mt + lc;
    if (cell <= 124) {
      const int i = cell / 25, rm = cell - 25 * i, j = rm / 5, k = rm - 5 * j;
      int tv[8];
      tv[0] = tid3r(i, j, k);
      tv[1] = 48 + pid2r(j, k);
      tv[2] = 64 + pid2r(i, k);
      tv[3] = 80 + pid2r(i, j);
      tv[4] = 96 + k;
      tv[5] = 101 + j;
      tv[6] = 106 + i;
      tv[7] = 111;
      #pragma unroll
      for (int e = 0; e < 8; ++e) {
        const unsigned b = 1u << (tv[e] & 31);
        const int dw = tv[e] >> 5;
        m0 |= (dw == 0) ? b : 0u;
        m1 |= (dw == 1) ? b : 0u;
        m2 |= (dw == 2) ? b : 0u;
        m3 |= (dw == 3) ? b : 0u;
      }
    }
    msk[mt][0] = m0; msk[mt][1] = m1; msk[mt][2] = m2; msk[mt][3] = m3;
  }
  bf16x8 af[8][4];                                  // pinned A-frags (0/1 bf16)
  #pragma unroll
  for (int mt = 0; mt < 8; ++mt)
    #pragma unroll
    for (int kt = 0; kt < 4; ++kt) {
      const unsigned by = (msk[mt][kt] >> (8 * grp)) & 0xFFu;
      unsigned fr[4];
      #pragma unroll
      for (int qd = 0; qd < 4; ++qd)
        fr[qd] = (((by >> (2 * qd)) & 1u) * 0x3F80u) |
                 (((by >> (2 * qd + 1)) & 1u) * 0x3F800000u);
      af[mt][kt] = __builtin_bit_cast(bf16x8, *(const bf16x8*)fr);
    }
  __syncthreads();

  auto ftfrag = [&](int row0, int kt) -> bf16x8 {
    return *(const bf16x8*)(&FT[row0 + lc][8 * grp + 32 * kt]);
  };
  auto twrite64 = [&](int s, int t0, const f32x4& a) {
    uint2 pk;
    pk.x = (unsigned)f2bf(a[0]) | ((unsigned)f2bf(a[1]) << 16);
    pk.y = (unsigned)f2bf(a[2]) | ((unsigned)f2bf(a[3]) << 16);
    *(uint2*)(Tlds + t_addr(s, t0)) = pk;
  };

  for (int uu = 0; uu < nu; ++uu) {
    const int u = u0 + uu;
    const int side = u & 1;

    // ================= Phase A: features -> FT; + tail(u-1) =================
    {
      const int d = tid & 63, q = tid >> 6;
      const int* xn = x + u * 5;
      float vv[5];
      #pragma unroll
      for (int i = 0; i < 5; ++i) vv[i] = fmaxf(embed[xn[i] * 64 + d], 0.f);
      const float S = vv[0] + vv[1] + vv[2] + vv[3] + vv[4];
      const float S2 = S * S, S3 = S2 * S;
      float p2[15];
      #pragma unroll
      for (int a = 0; a < 5; ++a)
        #pragma unroll
        for (int b = a; b < 5; ++b) p2[pid2c(a, b)] = vv[a] * vv[b];
      // triples rows 0..34, split 14/14/7 across q=0,1,2
      #pragma unroll
      for (int a = 0; a < 5; ++a)
        #pragma unroll
        for (int b = a; b < 5; ++b)
          #pragma unroll
          for (int c = b; c < 5; ++c) {
            const int c3 = tid3c(a, b, c);
            const int qq = (c3 < 14) ? 0 : (c3 < 28) ? 1 : 2;
            if (q == qq) FT[c3][d] = f2bf(p2[pid2c(a, b)] * vv[c]);
          }
      // S*pair rows 48..62: q2 gets p 0..7, q3 gets 8..14
      #pragma unroll
      for (int p = 0; p < 15; ++p) {
        const int qq = (p < 8) ? 2 : 3;
        if (q == qq) FT[48 + p][d] = f2bf(S * p2[p]);
      }
      if (q == 3) {
        #pragma unroll
        for (int i = 0; i < 5; ++i) FT[64 + i][d] = f2bf(S2 * vv[i]);
        FT[69][d] = f2bf(S3);
      }
    }
    if (uu > 0 && tid < 128) {                       // tail(u-1): z, FC partial
      const int o = tid;
      const int sp = (u - 1) & 1;
      const float* bo = sp ? bout2 : bout1;
      const float z = fmaxf(scratch[0][o] + scratch[1][o] + bo[o], 0.f);
      const float* fw = fcw + sp * 256;
      float p0 = z * fw[2 * o], p1 = z * fw[2 * o + 1];
      #pragma unroll
      for (int off = 32; off; off >>= 1) {
        p0 += __shfl_down(p0, off);
        p1 += __shfl_down(p1, off);
      }
      if ((tid & 63) == 0) { fcp[(tid >> 6) * 2] = p0; fcp[(tid >> 6) * 2 + 1] = p1; }
    }
    __syncthreads();

    // ================= Phase G: GEMM1 -> T (own rows) -> GEMM2 -> hbar =======
    {
      if (tid == 0 && uu > 0) {                      // pbuf(u-1) from fcp
        pbuf[2 * (u - 1)]     = fcp[0] + fcp[2];
        pbuf[2 * (u - 1) + 1] = fcp[1] + fcp[3];
      }
      const ushort* CTs = ct + side * (8 * 128 * 64);
      auto cfrag = [&](int bank, int ntI, int kt) -> bf16x8 {
        const ushort* rp = CTs + (size_t)(bank * 128 + 32 * w + 16 * ntI + lc) * 64
                         + 32 * kt + 8 * grp;
        return *(const bf16x8*)rp;
      };
      const int sA = 32 * w + lc;                    // nt0 row
      const int sB = sA + 16;                        // nt1 row

      // --- GEMM1 b0: triples, T cols 0..47 ---
      {
        const bf16x8 B00 = cfrag(0, 0, 0), B01 = cfrag(0, 0, 1);
        const bf16x8 B10 = cfrag(0, 1, 0), B11 = cfrag(0, 1, 1);
        #pragma unroll
        for (int mtl = 0; mtl < 3; ++mtl) {
          const bf16x8 A0 = ftfrag(16 * mtl, 0), A1 = ftfrag(16 * mtl, 1);
          f32x4 a = {0.f, 0.f, 0.f, 0.f};
          a = MFMA(A0, B00, a, 0, 0, 0);
          a = MFMA(A1, B01, a, 0, 0, 0);
          twrite64(sA, 16 * mtl + 4 * grp, a);
          f32x4 b = {0.f, 0.f, 0.f, 0.f};
          b = MFMA(A0, B10, b, 0, 0, 0);
          b = MFMA(A1, B11, b, 0, 0, 0);
          twrite64(sB, 16 * mtl + 4 * grp, b);
        }
      }
      // --- GEMM1 b1..b3: S*pairs, T cols 48..95 ---
      {
        const bf16x8 AP0 = ftfrag(48, 0), AP1 = ftfrag(48, 1);
        #pragma unroll
        for (int bank = 1; bank <= 3; ++bank) {
          const int tb = 48 + 16 * (bank - 1);
          const bf16x8 B0 = cfrag(bank, 0, 0), B1 = cfrag(bank, 0, 1);
          f32x4 a = {0.f, 0.f, 0.f, 0.f};
          a = MFMA(AP0, B0, a, 0, 0, 0);
          a = MFMA(AP1, B1, a, 0, 0, 0);
          twrite64(sA, tb + 4 * grp, a);
          const bf16x8 C0 = cfrag(bank, 1, 0), C1 = cfrag(bank, 1, 1);
          f32x4 b = {0.f, 0.f, 0.f, 0.f};
          b = MFMA(AP0, C0, b, 0, 0, 0);
          b = MFMA(AP1, C1, b, 0, 0, 0);
          twrite64(sB, tb + 4 * grp, b);
        }
      }
      // --- GEMM1 b4..b7: S2v / S3, T cols 96..111 (scalar extracts) ---
      {
        const bf16x8 AS0 = ftfrag(64, 0), AS1 = ftfrag(64, 1);
        #pragma unroll
        for (int bank = 4; bank <= 7; ++bank) {
          const int tb = (bank < 7) ? (96 + 5 * (bank - 4)) : 111;
          #pragma unroll
          for (int ntI = 0; ntI < 2; ++ntI) {
            const int s = (ntI == 0) ? sA : sB;
            const bf16x8 B0 = cfrag(bank, ntI, 0), B1 = cfrag(bank, ntI, 1);
            f32x4 a = {0.f, 0.f, 0.f, 0.f};
            a = MFMA(AS0, B0, a, 0, 0, 0);
            a = MFMA(AS1, B1, a, 0, 0, 0);
            if (bank < 7) {                          // feature rows 0..4 -> t tb..tb+4
              if (grp == 0) {
                #pragma unroll
                for (int r = 0; r < 4; ++r) Tlds[t_addr(s, tb + r)] = f2bf(a[r]);
              } else if (grp == 1) {
                Tlds[t_addr(s, tb + 4)] = f2bf(a[0]); // row 4
              }
            } else {                                 // S3 at feature row 5 -> t 111
              if (grp == 1) Tlds[t_addr(s, 111)] = f2bf(a[1]);
            }
          }
        }
      }
      // --- GEMM2: E = M*T + bias; relu+mean in registers (same-wave T reads) ---
      const float* bi = side ? bias2 : bias1;
      #pragma unroll
      for (int ntI = 0; ntI < 2; ++ntI) {
        const int s = (ntI == 0) ? sA : sB;
        const float bsv = bi[s];
        f32x4 acc[8];
        #pragma unroll
        for (int mt = 0; mt < 8; ++mt) acc[mt] = {bsv, bsv, bsv, bsv};
        #pragma unroll
        for (int kt = 0; kt < 4; ++kt) {
          const bf16x8 Bf = *(const bf16x8*)(Tlds + t_addr(s, 32 * kt + 8 * grp));
          #pragma unroll
          for (int mt = 0; mt < 8; ++mt)
            acc[mt] = MFMA(af[mt][kt], Bf, acc[mt], 0, 0, 0);
        }
        float hs = 0.f;
        #pragma unroll
        for (int mt = 0; mt < 8; ++mt)
          #pragma unroll
          for (int r = 0; r < 4; ++r) {
            float v = fmaxf(acc[mt][r], 0.f);
            if (mt == 7 && r >= 1) v = (grp == 3) ? 0.f : v;  // pad cells 125..127
            hs += v;
          }
        hs += __shfl_xor(hs, 16);
        hs += __shfl_xor(hs, 32);
        if (grp == 0) hbar[s] = hs * (1.f / 125.f);
      }
    }
    __syncthreads();

    // ================= Phase C: z-parts = hbar @ wout (f32) ==================
    {
      const int o = tid & 127, shh = tid >> 7;
      float r;
      if (wt != nullptr) {
        const f32x4* wv = (const f32x4*)(wt + side * 16384 + o * 128 + shh * 64);
        const f32x4* hv = (const f32x4*)(&hbar[shh * 64]);
        float a0 = 0.f, a1 = 0.f, a2 = 0.f, a3 = 0.f;
        #pragma unroll
        for (int qq = 0; qq < 16; ++qq) {
          const f32x4 wq = wv[qq];
          const f32x4 hq = hv[qq];
          a0 = fmaf(hq[0], wq[0], a0);
          a1 = fmaf(hq[1], wq[1], a1);
          a2 = fmaf(hq[2], wq[2], a2);
          a3 = fmaf(hq[3], wq[3], a3);
        }
        r = (a0 + a1) + (a2 + a3);
      } else {
        const float* W = side ? wout2 : wout1;
        float a0 = 0.f, a1 = 0.f;
        #pragma unroll 8
        for (int ss = 64 * shh; ss < 64 * shh + 64; ss += 2) {
          a0 = fmaf(hbar[ss], W[ss * 128 + o], a0);
          a1 = fmaf(hbar[ss + 1], W[(ss + 1) * 128 + o], a1);
        }
        r = a0 + a1;
      }
      scratch[shh][o] = r;
    }
    __syncthreads();
  }

  // ---- epilogue: tail + pbuf for last unit ----
  {
    const int ul = u0 + nu - 1;
    if (tid < 128) {
      const int o = tid;
      const int sp = ul & 1;
      const float* bo = sp ? bout2 : bout1;
      const float z = fmaxf(scratch[0][o] + scratch[1][o] + bo[o], 0.f);
      const float* fw = fcw + sp * 256;
      float p0 = z * fw[2 * o], p1 = z * fw[2 * o + 1];
      #pragma unroll
      for (int off = 32; off; off >>= 1) {
        p0 += __shfl_down(p0, off);
        p1 += __shfl_down(p1, off);
      }
      if ((tid & 63) == 0) { fcp[(tid >> 6) * 2] = p0; fcp[(tid >> 6) * 2 + 1] = p1; }
    }
    __syncthreads();
    if (tid == 0) {
      pbuf[2 * ul]     = fcp[0] + fcp[2];
      pbuf[2 * ul + 1] = fcp[1] + fcp[3];
    }
  }
}

// ---------- final: out[n,c] = pbuf[2n][c] + pbuf[2n+1][c] + fcb[c] ----------
__global__ __launch_bounds__(256)
void fc_final(const float* __restrict__ pbuf, const float* __restrict__ fcb,
              float* __restrict__ out, int nout) {
  const int t = blockIdx.x * 256 + threadIdx.x;
  if (t < nout) {
    const int n = t >> 1, c = t & 1;
    out[t] = pbuf[4 * n + c] + pbuf[4 * n + 2 + c] + fcb[c];
  }
}

extern "C" void kernel_launch(void* const* d_in, const int* in_sizes, int n_in,
                              void* d_out, int out_size, void* d_ws, size_t ws_size,
                              hipStream_t stream) {
  const int*   x      = (const int*)  d_in[0];
  const float* embed  = (const float*)d_in[1];
  const float* coefs1 = (const float*)d_in[2];
  const float* bias1  = (const float*)d_in[3];
  const float* wout1  = (const float*)d_in[4];
  const float* bout1  = (const float*)d_in[5];
  const float* coefs2 = (const float*)d_in[6];
  const float* bias2  = (const float*)d_in[7];
  const float* wout2  = (const float*)d_in[8];
  const float* bout2  = (const float*)d_in[9];
  const float* fcw    = (const float*)d_in[10];
  const float* fcb    = (const float*)d_in[11];
  float* out = (float*)d_out;

  // ws layout: pbuf (32 KiB) | CT (256 KiB) | WT (128 KiB, optional)
  float*  pbuf = (float*)d_ws;
  ushort* ct   = (ushort*)((char*)d_ws + 32768);
  const int do_wt = (ws_size >= (size_t)(32768 + 262144 + 131072)) ? 1 : 0;
  float*  wt   = do_wt ? (float*)((char*)d_ws + 32768 + 262144) : nullptr;

  const int batch  = in_sizes[0] / 10;     // x: (B, 2, 5)
  const int nunits = batch * 2;
  const int nblk   = (nunits + 7) / 8;

  cvt_prep_kernel<<<640, 256, 0, stream>>>(coefs1, coefs2, wout1, wout2, ct, wt, do_wt);
  dota2_eq3_fused<<<nblk, 256, 0, stream>>>(
      x, embed, bias1, bias2, bout1, bout2, wout1, wout2, fcw, ct, wt, pbuf, nunits);
  fc_final<<<(nunits + 255) / 256, 256, 0, stream>>>(pbuf, fcb, out, nunits);
}

// Round 9
// 85.587 us; speedup vs baseline: 1.6008x; 1.6008x over previous
//
#include <hip/hip_runtime.h>

// Dota2Eq3Embed round 9: wave-local GEMM1 + block-uniform assembly.
// Per unit u=(sample,side): v[i][d]=relu(embed[x[u*5+i]][d]).
// 8 equivariant contractions reduce to per-channel table T (96 cols):
//   g0: 0..34 (triples), b1: 48..62, b2: 64..78, b3: 80..94,
//   m4: 96..100, m5: 104..108, m6: 112..116, a7: 120   (bf16, stride 136)
// GEMM1 per wave (2 n-tiles of 16 channels): mfma(FT_frag, CTfrag) -> T.
// Assembly: 256 thr = 128 ch x 2 cell-halves, T-row in registers (16xb128,
// sched_barrier pins), hoisted 125-cell relu-sum. wout (1/125 folded into
// transposed WT) -> z -> per-unit FC partials -> pbuf; fc_final combines.
// 4 barriers/unit; grid 768 = exactly 3 blocks/CU (LDS 47.2 KB).

typedef __attribute__((ext_vector_type(8))) short bf16x8;
typedef __attribute__((ext_vector_type(4))) float f32x4;
typedef __attribute__((ext_vector_type(4))) unsigned u32x4;

#define DEV __device__ __forceinline__
#define MFMA __builtin_amdgcn_mfma_f32_16x16x32_bf16

DEV constexpr int pid2(int a, int b) {
  int x = a < b ? a : b, y = a < b ? b : a;
  return x * (9 - x) / 2 + y;                 // 15 pairs, lex
}
DEV constexpr int tid3(int i, int j, int k) {
  int a = i, b = j, c = k, t;
  if (a > b) { t = a; a = b; b = t; }
  if (b > c) { t = b; b = c; c = t; }
  if (a > b) { t = a; a = b; b = t; }
  return a * (a * a - 18 * a + 107) / 6 + (b - a) * (11 - a - b) / 2 + (c - b);
}
DEV ushort f2bf(float f) {                     // RTNE
  unsigned u = __builtin_bit_cast(unsigned, f);
  return (ushort)((u + 0x7FFFu + ((u >> 16) & 1u)) >> 16);
}
DEV unsigned pk2(float a, float b) {
  return (unsigned)f2bf(a) | ((unsigned)f2bf(b) << 16);
}

// ---- prep: CTfrag[side][bank][kt][nt][lane][8] bf16; WT[side][o][s]/125 ----
__global__ __launch_bounds__(256)
void prep_kernel(const float* __restrict__ c1, const float* __restrict__ c2,
                 const float* __restrict__ w1, const float* __restrict__ w2,
                 ushort* __restrict__ ctf, float* __restrict__ wt, int do_wt) {
  const int idx = blockIdx.x * 256 + threadIdx.x;
  if (idx < 131072) {
    const int e = idx & 7, l = (idx >> 3) & 63, nt = (idx >> 9) & 7,
              kt = (idx >> 12) & 1, bank = (idx >> 13) & 7, side = (idx >> 16) & 1;
    const int d = 32 * kt + 8 * (l >> 4) + e;
    const int s = 16 * nt + (l & 15);
    ctf[idx] = f2bf((side ? c2 : c1)[(d * 128 + s) * 8 + bank]);
  } else if (do_wt) {
    const int j = idx - 131072;
    if (j < 65536) {
      const int s = j & 127, o = (j >> 7) & 127, side = j >> 14;
      wt[j] = (side ? w2 : w1)[s * 128 + o] * (1.f / 125.f);
    }
  }
}

__global__ __launch_bounds__(256, 3)
void eq3_wavegemm(const int* __restrict__ x, const float* __restrict__ embed,
                  const float* __restrict__ bias1, const float* __restrict__ bias2,
                  const float* __restrict__ bout1, const float* __restrict__ bout2,
                  const float* __restrict__ wout1, const float* __restrict__ wout2,
                  const float* __restrict__ fcw,
                  const ushort* __restrict__ ctf, const float* __restrict__ wt,
                  float* __restrict__ pbuf, int nunits)
{
  __shared__ ushort FT[80 * 64];    // bf16 features, XOR-swizzled rows, 10240 B
  __shared__ ushort TS[8 * 2184];   // bf16 T, [nti][16ch][136], 34944 B
  __shared__ float  S2[256];        // asm partials [half][ch]
  __shared__ float  SW[256];        // wout partials [h][o]
  __shared__ float  fcp[4];

  const int tid = threadIdx.x;
  const int w = tid >> 6, l = tid & 63, grp = l >> 4, lc = l & 15;

  // zero FT pad rows once per block (rows 35..47, 63, 70..79)
  for (int e = tid; e < 24 * 64; e += 256) {
    const int r = e >> 6, d = e & 63;
    const int row = (r < 13) ? 35 + r : ((r == 13) ? 63 : 70 + (r - 14));
    FT[(row * 64 + d) ^ ((row & 7) << 3)] = 0;
  }
  int uprev = -1;

  for (int u = blockIdx.x; u < nunits; u += gridDim.x) {
    const int side = u & 1;

    // ================= Phase A: features -> FT (q-split rows) =================
    {
      const int d = tid & 63, q = tid >> 6;
      const int* xn = x + u * 5;
      float v[5];
      #pragma unroll
      for (int i = 0; i < 5; ++i) v[i] = fmaxf(embed[xn[i] * 64 + d], 0.f);
      const float Sv = v[0] + v[1] + v[2] + v[3] + v[4];
      const float Sq = Sv * Sv, Sc = Sq * Sv;
      float p2a[15];
      {
        int c2 = 0;
        #pragma unroll
        for (int a = 0; a < 5; ++a)
          #pragma unroll
          for (int b = a; b < 5; ++b) { p2a[c2] = v[a] * v[b]; ++c2; }
      }
      {
        int c3 = 0;
        #pragma unroll
        for (int a = 0; a < 5; ++a)
          #pragma unroll
          for (int b = a; b < 5; ++b)
            #pragma unroll
            for (int c = b; c < 5; ++c) {
              const int qq = (c3 < 14) ? 0 : ((c3 < 28) ? 1 : 2);
              if (q == qq)
                FT[(c3 * 64 + d) ^ ((c3 & 7) << 3)] = f2bf(p2a[pid2(a, b)] * v[c]);
              ++c3;
            }
      }
      #pragma unroll
      for (int p = 0; p < 15; ++p) {
        const int qq = (p < 7) ? 2 : 3;
        const int row = 48 + p;
        if (q == qq) FT[(row * 64 + d) ^ ((row & 7) << 3)] = f2bf(Sv * p2a[p]);
      }
      if (q == 3) {
        #pragma unroll
        for (int i = 0; i < 5; ++i) {
          const int row = 64 + i;
          FT[(row * 64 + d) ^ ((row & 7) << 3)] = f2bf(Sq * v[i]);
        }
        FT[(69 * 64 + d) ^ ((69 & 7) << 3)] = f2bf(Sc);
      }
    }
    __syncthreads();

    // deferred FC tail of previous unit
    if (uprev >= 0 && tid == 0) {
      pbuf[2 * uprev]     = fcp[0] + fcp[2];
      pbuf[2 * uprev + 1] = fcp[1] + fcp[3];
    }

    // ================= Phase G: wave-local GEMM1 -> TS (bf16) =================
    {
      const ushort* cbase = ctf + side * 65536;
      #pragma unroll
      for (int sub = 0; sub < 2; ++sub) {
        const int nti = 2 * w + sub;
        auto FR = [&](int t0, int kt) -> bf16x8 {
          const int t = t0 + lc;
          return *(const bf16x8*)(FT + ((t * 64 + 32 * kt + 8 * grp) ^ ((t & 7) << 3)));
        };
        auto CR = [&](int bank, int kt) -> bf16x8 {
          return *(const bf16x8*)(cbase + (((bank * 2 + kt) * 8 + nti) * 64 + l) * 8);
        };
        ushort* tb = TS + nti * 2184 + lc * 136;
        f32x4 a;
        // g0 tiles (bank 0): cols 0..34
        a = {0.f, 0.f, 0.f, 0.f};
        a = MFMA(FR(0, 0), CR(0, 0), a, 0, 0, 0);
        a = MFMA(FR(0, 1), CR(0, 1), a, 0, 0, 0);
        { uint2 t2; t2.x = pk2(a[0], a[1]); t2.y = pk2(a[2], a[3]);
          *reinterpret_cast<uint2*>(tb + 4 * grp) = t2; }
        a = {0.f, 0.f, 0.f, 0.f};
        a = MFMA(FR(16, 0), CR(0, 0), a, 0, 0, 0);
        a = MFMA(FR(16, 1), CR(0, 1), a, 0, 0, 0);
        { uint2 t2; t2.x = pk2(a[0], a[1]); t2.y = pk2(a[2], a[3]);
          *reinterpret_cast<uint2*>(tb + 16 + 4 * grp) = t2; }
        a = {0.f, 0.f, 0.f, 0.f};
        a = MFMA(FR(32, 0), CR(0, 0), a, 0, 0, 0);
        a = MFMA(FR(32, 1), CR(0, 1), a, 0, 0, 0);
        if (grp == 0) {
          *reinterpret_cast<unsigned*>(tb + 32) = pk2(a[0], a[1]);
          tb[34] = f2bf(a[2]);
        }
        // pair tiles (banks 1-3): cols 48/64/80 + pid
        {
          const bf16x8 A0 = FR(48, 0), A1 = FR(48, 1);
          #pragma unroll
          for (int bk = 1; bk <= 3; ++bk) {
            const int cb = 48 + 16 * (bk - 1);
            a = {0.f, 0.f, 0.f, 0.f};
            a = MFMA(A0, CR(bk, 0), a, 0, 0, 0);
            a = MFMA(A1, CR(bk, 1), a, 0, 0, 0);
            if (grp < 3) {
              uint2 t2; t2.x = pk2(a[0], a[1]); t2.y = pk2(a[2], a[3]);
              *reinterpret_cast<uint2*>(tb + cb + 4 * grp) = t2;
            } else {
              *reinterpret_cast<unsigned*>(tb + cb + 12) = pk2(a[0], a[1]);
              tb[cb + 14] = f2bf(a[2]);
            }
          }
        }
        // m tiles (banks 4-6) cols 96/104/112; a7 (bank 7) col 120
        {
          const bf16x8 A0 = FR(64, 0), A1 = FR(64, 1);
          #pragma unroll
          for (int bk = 4; bk <= 6; ++bk) {
            const int cb = 96 + 8 * (bk - 4);
            a = {0.f, 0.f, 0.f, 0.f};
            a = MFMA(A0, CR(bk, 0), a, 0, 0, 0);
            a = MFMA(A1, CR(bk, 1), a, 0, 0, 0);
            if (grp == 0) {
              uint2 t2; t2.x = pk2(a[0], a[1]); t2.y = pk2(a[2], a[3]);
              *reinterpret_cast<uint2*>(tb + cb) = t2;
            } else if (grp == 1) {
              tb[cb + 4] = f2bf(a[0]);
            }
          }
          a = {0.f, 0.f, 0.f, 0.f};
          a = MFMA(A0, CR(7, 0), a, 0, 0, 0);
          a = MFMA(A1, CR(7, 1), a, 0, 0, 0);
          if (grp == 1) tb[120] = f2bf(a[1]);
        }
      }
    }
    __syncthreads();

    // ================= Phase asm: 128 ch x 2 halves, uniform ==================
    {
      const int ch = tid & 127, half = tid >> 7;
      const ushort* trow = TS + (ch >> 4) * 2184 + (ch & 15) * 136;
      u32x4 R[16];
      #pragma unroll
      for (int j = 0; j < 16; ++j) R[j] = *(const u32x4*)(trow + 8 * j);
      __builtin_amdgcn_sched_barrier(0);
      auto ext = [&](int c) -> float {
        const unsigned wv = R[c >> 3][(c >> 1) & 3];
        return __builtin_bit_cast(float, (c & 1) ? (wv & 0xFFFF0000u) : (wv << 16));
      };
      const float* bi = side ? bias2 : bias1;
      const float base = ext(120) + bi[ch];
      float hs = 0.f;
      #define CELLK(i, j, k)                                                      \
        hs += fmaxf(pij + ext(96 + (k)) + ext(64 + pid2(i, k)) +                  \
                    ext(48 + pid2(j, k)) + ext(tid3(i, j, k)), 0.f);
      if (half == 0) {            // cells 0..62
        #pragma unroll
        for (int i = 0; i < 2; ++i) {
          const float pi = base + ext(112 + i);
          #pragma unroll
          for (int j = 0; j < 5; ++j) {
            const float pij = pi + ext(104 + j) + ext(80 + pid2(i, j));
            #pragma unroll
            for (int k = 0; k < 5; ++k) CELLK(i, j, k)
          }
        }
        {
          const float pi = base + ext(112 + 2);
          #pragma unroll
          for (int j = 0; j < 2; ++j) {
            const float pij = pi + ext(104 + j) + ext(80 + pid2(2, j));
            #pragma unroll
            for (int k = 0; k < 5; ++k) CELLK(2, j, k)
          }
          {
            const float pij = pi + ext(104 + 2) + ext(80 + pid2(2, 2));
            #pragma unroll
            for (int k = 0; k < 3; ++k) CELLK(2, 2, k)
          }
        }
      } else {                    // cells 63..124
        {
          const float pi = base + ext(112 + 2);
          {
            const float pij = pi + ext(104 + 2) + ext(80 + pid2(2, 2));
            #pragma unroll
            for (int k = 3; k < 5; ++k) CELLK(2, 2, k)
          }
          #pragma unroll
          for (int j = 3; j < 5; ++j) {
            const float pij = pi + ext(104 + j) + ext(80 + pid2(2, j));
            #pragma unroll
            for (int k = 0; k < 5; ++k) CELLK(2, j, k)
          }
        }
        #pragma unroll
        for (int i = 3; i < 5; ++i) {
          const float pi = base + ext(112 + i);
          #pragma unroll
          for (int j = 0; j < 5; ++j) {
            const float pij = pi + ext(104 + j) + ext(80 + pid2(i, j));
            #pragma unroll
            for (int k = 0; k < 5; ++k) CELLK(i, j, k)
          }
        }
      }
      #undef CELLK
      S2[half * 128 + ch] = hs;
    }
    __syncthreads();

    // ================= Phase wout: 256 thr = 128 o x 2 s-halves ===============
    {
      const int o = tid & 127, h = tid >> 7;
      float r;
      if (wt != nullptr) {
        const f32x4* wv = (const f32x4*)(wt + side * 16384 + o * 128 + h * 64);
        const f32x4* pa = (const f32x4*)(S2 + h * 64);
        const f32x4* pb = (const f32x4*)(S2 + 128 + h * 64);
        float a0 = 0.f, a1 = 0.f, a2 = 0.f, a3 = 0.f;
        #pragma unroll
        for (int q2 = 0; q2 < 16; ++q2) {
          const f32x4 hq = pa[q2] + pb[q2];
          const f32x4 wq = wv[q2];
          a0 = fmaf(hq[0], wq[0], a0);
          a1 = fmaf(hq[1], wq[1], a1);
          a2 = fmaf(hq[2], wq[2], a2);
          a3 = fmaf(hq[3], wq[3], a3);
        }
        r = (a0 + a1) + (a2 + a3);
      } else {
        const float* W = side ? wout2 : wout1;
        float acc = 0.f;
        #pragma unroll 8
        for (int s = 64 * h; s < 64 * h + 64; ++s)
          acc = fmaf((S2[s] + S2[128 + s]) * (1.f / 125.f), W[s * 128 + o], acc);
        r = acc;
      }
      SW[h * 128 + o] = r;
    }
    __syncthreads();

    // ================= Phase z/FC: partials -> fcp (no barrier) ===============
    if (tid < 128) {
      const int o = tid;
      const float* bo = side ? bout2 : bout1;
      const float z = fmaxf(SW[o] + SW[128 + o] + bo[o], 0.f);
      const float* fw = fcw + side * 256;
      float p0 = z * fw[2 * o], p1 = z * fw[2 * o + 1];
      #pragma unroll
      for (int off = 32; off; off >>= 1) {
        p0 += __shfl_down(p0, off);
        p1 += __shfl_down(p1, off);
      }
      if ((tid & 63) == 0) { fcp[(tid >> 6) * 2] = p0; fcp[(tid >> 6) * 2 + 1] = p1; }
    }
    uprev = u;
  }

  if (uprev >= 0) {
    __syncthreads();
    if (tid == 0) {
      pbuf[2 * uprev]     = fcp[0] + fcp[2];
      pbuf[2 * uprev + 1] = fcp[1] + fcp[3];
    }
  }
}

// ---------- final: out[n,c] = pbuf[2n][c] + pbuf[2n+1][c] + fcb[c] ----------
__global__ __launch_bounds__(256)
void fc_final(const float* __restrict__ pbuf, const float* __restrict__ fcb,
              float* __restrict__ out, int nout) {
  const int t = blockIdx.x * 256 + threadIdx.x;
  if (t < nout) {
    const int n = t >> 1, c = t & 1;
    out[t] = pbuf[4 * n + c] + pbuf[4 * n + 2 + c] + fcb[c];
  }
}

extern "C" void kernel_launch(void* const* d_in, const int* in_sizes, int n_in,
                              void* d_out, int out_size, void* d_ws, size_t ws_size,
                              hipStream_t stream) {
  const int*   x      = (const int*)  d_in[0];
  const float* embed  = (const float*)d_in[1];
  const float* coefs1 = (const float*)d_in[2];
  const float* bias1  = (const float*)d_in[3];
  const float* wout1  = (const float*)d_in[4];
  const float* bout1  = (const float*)d_in[5];
  const float* coefs2 = (const float*)d_in[6];
  const float* bias2  = (const float*)d_in[7];
  const float* wout2  = (const float*)d_in[8];
  const float* bout2  = (const float*)d_in[9];
  const float* fcw    = (const float*)d_in[10];
  const float* fcb    = (const float*)d_in[11];
  float* out = (float*)d_out;

  // ws: pbuf (32 KiB) | CTfrag (256 KiB) | WT (128 KiB, optional)
  float*  pbuf = (float*)d_ws;
  ushort* ctf  = (ushort*)((char*)d_ws + 32768);
  const int do_wt = (ws_size >= (size_t)(32768 + 262144 + 131072)) ? 1 : 0;
  float*  wt   = do_wt ? (float*)((char*)d_ws + 32768 + 262144) : nullptr;

  const int batch  = in_sizes[0] / 10;     // x: (B, 2, 5)
  const int nunits = batch * 2;

  prep_kernel<<<768, 256, 0, stream>>>(coefs1, coefs2, wout1, wout2, ctf, wt, do_wt);
  eq3_wavegemm<<<768, 256, 0, stream>>>(
      x, embed, bias1, bias2, bout1, bout2, wout1, wout2, fcw, ctf, wt, pbuf, nunits);
  fc_final<<<(nunits + 255) / 256, 256, 0, stream>>>(pbuf, fcb, out, nunits);
}